// Round 8
// baseline (153.306 us; speedup 1.0000x reference)
//
#include <hip/hip_runtime.h>
#include <hip/hip_bf16.h>
#include <cstdint>
#include <cstddef>
#include <math.h>

#define D 256
#define TEMP_INV 2.0f       // 1 / TEMPERATURE, TEMPERATURE = 0.5
#define EPS_NORM 1e-8f
#define NTILES 2080         // 64*65/2 upper-triangular 128x128 tiles
#define GEMM_GRID 1024      // persistent blocks; queue hands out 1024..2079

typedef __attribute__((ext_vector_type(8))) short bf16x8;
typedef __attribute__((ext_vector_type(4))) float f32x4;

// ---------------- kernel 1: normalize rows, write bf16 zn ----------------
// 512 blocks x 4 waves, grid-stride over 8192 rows (4 rows/wave).
__global__ void __launch_bounds__(256) normalize_rows(
    const float* __restrict__ zi, const float* __restrict__ zj,
    __hip_bfloat16* __restrict__ zn, float* __restrict__ out,
    int* __restrict__ queue, int B) {
  const int wid = threadIdx.x >> 6;
  const int lane = threadIdx.x & 63;
  if (blockIdx.x == 0 && threadIdx.x == 0) {
    out[0] = 0.0f;          // finalize accumulates into this
    queue[0] = GEMM_GRID;   // next tile id for the gemm work queue
  }
#pragma unroll
  for (int it = 0; it < 4; ++it) {
    int row = it * 2048 + blockIdx.x * 4 + wid;
    const float* src = (row < B) ? (zi + (size_t)row * D)
                                 : (zj + (size_t)(row - B) * D);
    float4 v = ((const float4*)src)[lane];
    float ss = v.x * v.x + v.y * v.y + v.z * v.z + v.w * v.w;
    for (int off = 32; off; off >>= 1) ss += __shfl_xor(ss, off);
    float rn = 1.0f / fmaxf(sqrtf(ss), EPS_NORM);
    union { ushort4 u; __hip_bfloat16 h[4]; } o;
    o.h[0] = __float2bfloat16(v.x * rn);
    o.h[1] = __float2bfloat16(v.y * rn);
    o.h[2] = __float2bfloat16(v.z * rn);
    o.h[3] = __float2bfloat16(v.w * rn);
    ((ushort4*)zn)[(size_t)row * (D / 4) + lane] = o.u;
  }
}

// ---------------- kernel 2: fused sim GEMM + exp + masked row/col sums ---
// R15 == R14 resubmit (R14 bench died on container acquisition, not the
// kernel): PERSISTENT blocks + atomic work queue + cross-tile prefetch.
// Ledger: only blocks/CU ever moved gemm time (4/CU=37us, 2/CU=52us);
// XCD chunking null; staging-path variants (gload_lds, dbuf, reg-stage)
// all null at fixed occupancy. Remaining structural costs:
// (a) tail quantization: 2080 tiles / 1024 resident = 2.03 rounds; the
//     last ~0.03 round runs ~32 blocks across 256 CUs (~12us at ~1% util);
// (b) per-tile cold start: decode + first-slab load latency amortized
//     over only 4 K-steps.
// Fix: grid=1024 (exactly 4/CU resident), block b starts on tile b; tiles
// 1024.. handed out by global atomicAdd queue (grabbed at k0i==0, ~3
// K-steps before use -> atomic latency covered; dynamic balancing).
// The k0i==3 prefetch slot (unused before) loads slab 0 of the NEXT tile,
// hiding every tile's cold start under the previous tile's MFMA+epilogue.
// No inter-block dependency: queue only hands out work, so termination
// does not require co-residency (no deadlock under partial residency).
// Also: __syncthreads between last ds_read and epilogue LDS reuse (WAR).
// Staging: lane-SEQUENTIAL float4 loads -> regs -> ds_write_b128 with XOR
// swizzle on the LDS ADDRESS (0 conflicts, verified R4-R9).
__device__ __forceinline__ void decode_tile(int t, int Nb, int& by, int& bx) {
  float fb = (2.0f * Nb + 1.0f -
              sqrtf((float)((2 * Nb + 1) * (2 * Nb + 1) - 8 * t))) * 0.5f;
  int y = (int)fb;
  while ((y + 1) * Nb - ((y + 1) * y) / 2 <= t) ++y;
  while (y * Nb - (y * (y - 1)) / 2 > t) --y;
  by = y;
  bx = y + (t - (y * Nb - (y * (y - 1)) / 2));
}

__global__ void __launch_bounds__(256, 4) ntxent_gemm(
    const __hip_bfloat16* __restrict__ zn,
    float* __restrict__ part, float* __restrict__ pos,
    int* __restrict__ queue, int B) {
  __shared__ __align__(16) __hip_bfloat16 Ash[128 * 64];  // 16 KB
  __shared__ __align__(16) __hip_bfloat16 Bsh[128 * 64];  // 16 KB
  __shared__ int nextT_sh;

  const int N = 2 * B;
  const int Nb = N / 128;  // 64

  const int tid = threadIdx.x;
  const int wid = tid >> 6;
  const int lane = tid & 63;
  const int wy = wid >> 1, wx = wid & 1;
  const int wrow0 = wid * 32;

  const int lr = lane >> 3;     // row within 8-row staging group (== r&7)
  const int c8 = lane & 7;      // 16B chunk, SEQUENTIAL in global memory
  const int frow = lane & 15;
  const int quad = lane >> 4;
  const int f7 = frow & 7;
  // LDS write: row r, chunk c8 ^ (r&7); r&7 == lr for every s (s*8 step)
  const int ldsoff = (wrow0 + lr) * 64 + (c8 ^ lr) * 8;
  const int stageoff = (wrow0 + lr) * D + c8 * 8;  // element offset in zn row

  int by, bx;
  decode_tile(blockIdx.x, Nb, by, bx);
  int bm = by * 128, bn = bx * 128;

  const __hip_bfloat16* gA = zn + (size_t)bm * D + stageoff;
  const __hip_bfloat16* gB = zn + (size_t)bn * D + stageoff;

  // prologue: stage slab k0=0 of the first tile
  float4 va0 = *(const float4*)(gA + 0 * 8 * D);
  float4 va1 = *(const float4*)(gA + 1 * 8 * D);
  float4 va2 = *(const float4*)(gA + 2 * 8 * D);
  float4 va3 = *(const float4*)(gA + 3 * 8 * D);
  float4 vb0 = *(const float4*)(gB + 0 * 8 * D);
  float4 vb1 = *(const float4*)(gB + 1 * 8 * D);
  float4 vb2 = *(const float4*)(gB + 2 * 8 * D);
  float4 vb3 = *(const float4*)(gB + 3 * 8 * D);

  while (true) {
    const bool isDiag = (by == bx);
    const bool isPos = (bx == by + B / 128);
    f32x4 acc[4][4] = {};
    int nt = 0, byN = 0, bxN = 0;

#pragma unroll
    for (int k0i = 0; k0i < 4; ++k0i) {
      if (k0i == 0 && tid == 0) nextT_sh = atomicAdd(queue, 1);
      __syncthreads();  // WAR: previous slab's LDS reads complete
      *(float4*)&Ash[ldsoff + 0 * 8 * 64] = va0;
      *(float4*)&Ash[ldsoff + 1 * 8 * 64] = va1;
      *(float4*)&Ash[ldsoff + 2 * 8 * 64] = va2;
      *(float4*)&Ash[ldsoff + 3 * 8 * 64] = va3;
      *(float4*)&Bsh[ldsoff + 0 * 8 * 64] = vb0;
      *(float4*)&Bsh[ldsoff + 1 * 8 * 64] = vb1;
      *(float4*)&Bsh[ldsoff + 2 * 8 * 64] = vb2;
      *(float4*)&Bsh[ldsoff + 3 * 8 * 64] = vb3;
      __syncthreads();
      if (k0i == 2) {
        nt = nextT_sh;  // written at k0i==0, ordered by barriers
        int ntc = (nt < NTILES) ? nt : 0;  // clamp: harmless in-bounds loads
        decode_tile(ntc, Nb, byN, bxN);
      }
      if (k0i < 3) {
        // prefetch next slab of current tile; lands under MFMA below
        const int k0 = (k0i + 1) * 64;
        va0 = *(const float4*)(gA + 0 * 8 * D + k0);
        va1 = *(const float4*)(gA + 1 * 8 * D + k0);
        va2 = *(const float4*)(gA + 2 * 8 * D + k0);
        va3 = *(const float4*)(gA + 3 * 8 * D + k0);
        vb0 = *(const float4*)(gB + 0 * 8 * D + k0);
        vb1 = *(const float4*)(gB + 1 * 8 * D + k0);
        vb2 = *(const float4*)(gB + 2 * 8 * D + k0);
        vb3 = *(const float4*)(gB + 3 * 8 * D + k0);
      } else {
        // prefetch slab 0 of the NEXT tile; lands under MFMA + epilogue
        gA = zn + (size_t)(byN * 128) * D + stageoff;
        gB = zn + (size_t)(bxN * 128) * D + stageoff;
        va0 = *(const float4*)(gA + 0 * 8 * D);
        va1 = *(const float4*)(gA + 1 * 8 * D);
        va2 = *(const float4*)(gA + 2 * 8 * D);
        va3 = *(const float4*)(gA + 3 * 8 * D);
        vb0 = *(const float4*)(gB + 0 * 8 * D);
        vb1 = *(const float4*)(gB + 1 * 8 * D);
        vb2 = *(const float4*)(gB + 2 * 8 * D);
        vb3 = *(const float4*)(gB + 3 * 8 * D);
      }
#pragma unroll
      for (int kk = 0; kk < 2; ++kk) {
        bf16x8 a[4], b[4];
#pragma unroll
        for (int i = 0; i < 4; ++i)
          a[i] = *(const bf16x8*)
              &Ash[(wy * 64 + i * 16 + frow) * 64 + ((kk * 4 + quad) ^ f7) * 8];
#pragma unroll
        for (int j = 0; j < 4; ++j)
          b[j] = *(const bf16x8*)
              &Bsh[(wx * 64 + j * 16 + frow) * 64 + ((kk * 4 + quad) ^ f7) * 8];
#pragma unroll
        for (int i = 0; i < 4; ++i)
#pragma unroll
          for (int j = 0; j < 4; ++j)
            acc[i][j] = __builtin_amdgcn_mfma_f32_16x16x32_bf16(
                a[i], b[j], acc[i][j], 0, 0, 0);
      }
    }

    // ---- epilogue: exp + masked row/col sums -> LDS combine -> part writes
    __syncthreads();  // ALL waves' ds_reads done before Ash reuse (WAR)
    float* red = (float*)&Ash[0];  // [0..255]: rowbuf[128][2] (x wx)
                                   // [256..511]: colbuf[128][2] (x wy)
    const int colq = lane & 15;
    float cs[4] = {0.0f, 0.0f, 0.0f, 0.0f};
#pragma unroll
    for (int i = 0; i < 4; ++i) {
#pragma unroll
      for (int r = 0; r < 4; ++r) {
        int rowloc = wy * 64 + i * 16 + quad * 4 + r;
        int row = bm + rowloc;
        float rs = 0.0f;
#pragma unroll
        for (int j = 0; j < 4; ++j) {
          int col = bn + wx * 64 + j * 16 + colq;
          float v = acc[i][j][r];
          float e = __expf(v * TEMP_INV);
          e = (isDiag && col == row) ? 0.0f : e;
          rs += e;
          cs[j] += e;
          if (isPos && col == row + B) { pos[row] = v; pos[col] = v; }
        }
        rs += __shfl_xor(rs, 1);
        rs += __shfl_xor(rs, 2);
        rs += __shfl_xor(rs, 4);
        rs += __shfl_xor(rs, 8);
        if (colq == 0) red[rowloc * 2 + wx] = rs;
      }
    }
#pragma unroll
    for (int j = 0; j < 4; ++j) {
      float c = cs[j];
      c += __shfl_xor(c, 16);
      c += __shfl_xor(c, 32);
      if (quad == 0) red[256 + (wx * 64 + j * 16 + colq) * 2 + wy] = c;
    }
    __syncthreads();
    // part slot layout: for row idx in row-tile ty, slot s holds the
    // contribution of block (ty,s) row-sum (s>=ty) or block (s,ty)
    // col-sum (s<ty). Each slot written exactly once across all tiles.
    if (tid < 128) {
      part[(size_t)bx * N + bm + tid] = red[tid * 2] + red[tid * 2 + 1];
    } else if (!isDiag) {
      int tt = tid - 128;
      part[(size_t)by * N + bn + tt] =
          red[256 + tt * 2] + red[256 + tt * 2 + 1];
    }

    if (nt >= NTILES) break;
    by = byN; bx = bxN;
    bm = byN * 128; bn = bxN * 128;
  }
}

// ---------------- kernel 3: reduce partials + finalize loss scalar -------
// 32 blocks x 256 threads; thread owns one global row idx.
__global__ void __launch_bounds__(256) finalize(
    const float* __restrict__ part, const float* __restrict__ pos,
    float* __restrict__ out, int N) {
  const int idx = blockIdx.x * 256 + threadIdx.x;
  const int NS = N / 128;  // 64 slots
  float s = 0.0f;
#pragma unroll 8
  for (int k = 0; k < NS; ++k) s += part[(size_t)k * N + idx];
  float loss = __logf(s) - pos[idx] * TEMP_INV;
  for (int off = 32; off; off >>= 1) loss += __shfl_xor(loss, off);
  __shared__ float redsh[4];
  if ((threadIdx.x & 63) == 0) redsh[threadIdx.x >> 6] = loss;
  __syncthreads();
  if (threadIdx.x == 0) {
    float tt = redsh[0] + redsh[1] + redsh[2] + redsh[3];
    atomicAdd(out, tt / (float)N);
  }
}

extern "C" void kernel_launch(void* const* d_in, const int* in_sizes, int n_in,
                              void* d_out, int out_size, void* d_ws, size_t ws_size,
                              hipStream_t stream) {
  const float* zi = (const float*)d_in[0];
  const float* zj = (const float*)d_in[1];
  const int B = in_sizes[0] / D;  // 4096
  const int N = 2 * B;            // 8192

  __hip_bfloat16* zn = (__hip_bfloat16*)d_ws;
  float* pos = (float*)((char*)d_ws + (size_t)N * D * sizeof(__hip_bfloat16));
  float* part = pos + N;          // [N/128][N] floats = 2 MB
  int* queue = (int*)(part + (size_t)(N / 128) * N);

  normalize_rows<<<512, 256, 0, stream>>>(zi, zj, zn, (float*)d_out, queue, B);
  ntxent_gemm<<<GEMM_GRID, 256, 0, stream>>>(zn, part, pos, queue, B);
  finalize<<<N / 256, 256, 0, stream>>>(part, pos, (float*)d_out, N);
}